// Round 2
// baseline (386.859 us; speedup 1.0000x reference)
//
#include <hip/hip_runtime.h>

// Problem constants (match reference)
#define ZDIM  32
#define SP    (ZDIM * ZDIM * ZDIM)   // 32768 spatial positions
#define SP4   (SP / 4)               // 8192 float4 positions
#define CIN   256
#define COUT  4
#define BATCH 8

__device__ __forceinline__ void fma4(float4& a, const float4& v, float w) {
    a.x = fmaf(v.x, w, a.x);
    a.y = fmaf(v.y, w, a.y);
    a.z = fmaf(v.z, w, a.z);
    a.w = fmaf(v.w, w, a.w);
}

// Kernel 1 (v2): y[b,o,p] = sum_i weight[o,i]*(S[b,i]+1)*x[b,i,p] + prev[b,o,p]
// Memory-bound streaming x (256 MiB). v2: split the i-reduction 2-way across
// half-blocks (256-thread block, halves do i in [0,128) / [128,256)), combine
// via LDS. Doubles waves/CU 4 -> 8 so the memory pipe stays fed while the
// other half computes. float4 coalesced loads, unroll 8 for MLP.
__global__ __launch_bounds__(256) void modconv_kernel(
    const float* __restrict__ x, const float* __restrict__ S,
    const float* __restrict__ prev, const float* __restrict__ weight,
    float* __restrict__ y)
{
    __shared__ float  wm[CIN * COUT];   // [i][o], modulated weights
    __shared__ float4 part[COUT][128];  // upper-half partial sums, 8 KB

    const int b    = blockIdx.y;
    const int tid  = threadIdx.x;
    const int half = tid >> 7;          // 0 or 1
    const int t    = tid & 127;

    if (tid < CIN) {
        float s = S[b * CIN + tid] + 1.0f;
        #pragma unroll
        for (int o = 0; o < COUT; ++o)
            wm[tid * COUT + o] = weight[o * CIN + tid] * s;
    }
    __syncthreads();

    const int p4 = blockIdx.x * 128 + t;  // [0, 8192)
    const float4* xb = (const float4*)x + (size_t)b * CIN * SP4 + p4;

    float4 acc0 = {0,0,0,0}, acc1 = {0,0,0,0}, acc2 = {0,0,0,0}, acc3 = {0,0,0,0};
    const float4* wm4 = (const float4*)wm;  // wm4[i] = weights for o=0..3
    const int i0 = half << 7;               // 0 or 128

    #pragma unroll 1
    for (int i = i0; i < i0 + 128; i += 8) {
        float4 xv[8];
        #pragma unroll
        for (int u = 0; u < 8; ++u)
            xv[u] = xb[(size_t)(i + u) * SP4];
        #pragma unroll
        for (int u = 0; u < 8; ++u) {
            float4 w4 = wm4[i + u];   // LDS broadcast, conflict-free
            fma4(acc0, xv[u], w4.x);
            fma4(acc1, xv[u], w4.y);
            fma4(acc2, xv[u], w4.z);
            fma4(acc3, xv[u], w4.w);
        }
    }

    if (half) {
        part[0][t] = acc0;
        part[1][t] = acc1;
        part[2][t] = acc2;
        part[3][t] = acc3;
    }
    __syncthreads();
    if (!half) {
        const float4* pv = (const float4*)prev + (size_t)b * COUT * SP4 + p4;
        float4*       yb = (float4*)y          + (size_t)b * COUT * SP4 + p4;
        float4 po, pr;
        po = part[0][t]; pr = pv[0 * SP4];
        yb[0 * SP4] = make_float4(acc0.x + po.x + pr.x, acc0.y + po.y + pr.y,
                                  acc0.z + po.z + pr.z, acc0.w + po.w + pr.w);
        po = part[1][t]; pr = pv[1 * SP4];
        yb[1 * SP4] = make_float4(acc1.x + po.x + pr.x, acc1.y + po.y + pr.y,
                                  acc1.z + po.z + pr.z, acc1.w + po.w + pr.w);
        po = part[2][t]; pr = pv[2 * SP4];
        yb[2 * SP4] = make_float4(acc2.x + po.x + pr.x, acc2.y + po.y + pr.y,
                                  acc2.z + po.z + pr.z, acc2.w + po.w + pr.w);
        po = part[3][t]; pr = pv[3 * SP4];
        yb[3 * SP4] = make_float4(acc3.x + po.x + pr.x, acc3.y + po.y + pr.y,
                                  acc3.z + po.z + pr.z, acc3.w + po.w + pr.w);
    }
}

// Kernel 2: fused trilinear x2 upsample (half-pixel, jax.image.resize) + 3^3
// normalized blur [1,1.7,1] with edge padding. Separable: per axis, output 2k
// (even) = (1.175,2.275,0.25)/3.7 over y[k-1..k+1] (clamped); odd mirrored.
// One thread per 2x2x2 output cell; separable combine; float2 stores.
__global__ __launch_bounds__(256) void upblur_kernel(
    const float* __restrict__ y, float* __restrict__ out)
{
    constexpr float wA = 1.175f / 3.7f;   // near tap (even output)
    constexpr float wB = 2.275f / 3.7f;   // center tap
    constexpr float wC = 0.25f  / 3.7f;   // far tap

    const int c  = blockIdx.x * 256 + threadIdx.x;  // cell id in [0, 32*32768)
    const int ky = c & 31;
    const int kx = (c >> 5) & 31;
    const int kz = (c >> 10) & 31;
    const int bo = c >> 15;                          // (b*4+o) in [0,32)

    const float* yb = y + (size_t)bo * SP;
    const int zs[3] = { max(kz - 1, 0), kz, min(kz + 1, 31) };
    const int xs[3] = { max(kx - 1, 0), kx, min(kx + 1, 31) };
    const int ym = max(ky - 1, 0), yp = min(ky + 1, 31);

    // Stage 1: load 3x3x3 neighborhood, combine along y for both parities
    float se[3][3], so[3][3];
    #pragma unroll
    for (int a = 0; a < 3; ++a) {
        #pragma unroll
        for (int b2 = 0; b2 < 3; ++b2) {
            const float* row = yb + zs[a] * (ZDIM * ZDIM) + xs[b2] * ZDIM;
            float v0 = row[ym], v1 = row[ky], v2 = row[yp];
            se[a][b2] = wA * v0 + wB * v1 + wC * v2;   // yo = 2ky
            so[a][b2] = wC * v0 + wB * v1 + wA * v2;   // yo = 2ky+1
        }
    }
    // Stage 2: combine along x -> t[px][py][a]
    float t[2][2][3];
    #pragma unroll
    for (int a = 0; a < 3; ++a) {
        t[0][0][a] = wA * se[a][0] + wB * se[a][1] + wC * se[a][2];
        t[1][0][a] = wC * se[a][0] + wB * se[a][1] + wA * se[a][2];
        t[0][1][a] = wA * so[a][0] + wB * so[a][1] + wC * so[a][2];
        t[1][1][a] = wC * so[a][0] + wB * so[a][1] + wA * so[a][2];
    }
    // Stage 3: combine along z, write 2x2 float2 (yo pair contiguous)
    const size_t obase = (size_t)bo * (64 * 64 * 64)
                       + (size_t)(2 * kz) * (64 * 64)
                       + (size_t)(2 * kx) * 64 + 2 * ky;
    #pragma unroll
    for (int pz = 0; pz < 2; ++pz) {
        const float w0 = pz ? wC : wA;
        const float w2 = pz ? wA : wC;
        #pragma unroll
        for (int px = 0; px < 2; ++px) {
            float oy0 = w0 * t[px][0][0] + wB * t[px][0][1] + w2 * t[px][0][2];
            float oy1 = w0 * t[px][1][0] + wB * t[px][1][1] + w2 * t[px][1][2];
            *(float2*)(out + obase + (size_t)pz * (64 * 64) + px * 64) =
                make_float2(oy0, oy1);
        }
    }
}

extern "C" void kernel_launch(void* const* d_in, const int* in_sizes, int n_in,
                              void* d_out, int out_size, void* d_ws, size_t ws_size,
                              hipStream_t stream) {
    const float* x      = (const float*)d_in[0];  // (8,256,32,32,32)
    const float* S      = (const float*)d_in[1];  // (8,256)
    const float* prev   = (const float*)d_in[2];  // (8,4,32,32,32)
    const float* weight = (const float*)d_in[3];  // (4,256)
    float* out = (float*)d_out;                   // (8,4,64,64,64)
    float* y   = (float*)d_ws;                    // (8,4,32,32,32) scratch, 4 MiB

    dim3 g1(SP4 / 128, BATCH);  // 64 x 8 = 512 blocks of 256 threads
    modconv_kernel<<<g1, 256, 0, stream>>>(x, S, prev, weight, y);

    const int cells = BATCH * COUT * SP;  // 1,048,576 cells (2x2x2 outputs each)
    upblur_kernel<<<cells / 256, 256, 0, stream>>>(y, out);
}

// Round 4
// 359.905 us; speedup vs baseline: 1.0749x; 1.0749x over previous
//
#include <hip/hip_runtime.h>

// Problem constants (match reference)
#define ZDIM  32
#define SP    (ZDIM * ZDIM * ZDIM)   // 32768 spatial positions
#define SP2   (SP / 2)               // 16384 float2 positions
#define CIN   256
#define COUT  4
#define BATCH 8

// Native clang vector type — required by __builtin_nontemporal_load/store
// (HIP_vector_type float2 is a struct and is rejected).
typedef float vf2 __attribute__((ext_vector_type(2)));

__device__ __forceinline__ void fma2(vf2& a, const vf2& v, float w) {
    a.x = fmaf(v.x, w, a.x);
    a.y = fmaf(v.y, w, a.y);
}

// Kernel 1 (v3): y[b,o,p] = sum_i weight[o,i]*(S[b,i]+1)*x[b,i,p] + prev[b,o,p]
// Memory-bound streaming x (256 MiB, read exactly once -> nontemporal).
// v3: float2 granularity -> 1024 blocks x 128 thr = 8 waves/CU (2 waves/SIMD)
// so one wave issues loads while the other drains/computes. Unroll 8 keeps
// 8 x 512B loads in flight per wave. Per-batch modulated weight table
// (256 x 4) in LDS, broadcast reads (same-address -> conflict-free).
__global__ __launch_bounds__(128) void modconv_kernel(
    const float* __restrict__ x, const float* __restrict__ S,
    const float* __restrict__ prev, const float* __restrict__ weight,
    float* __restrict__ y)
{
    __shared__ float wm[CIN * COUT];  // [i][o]
    const int b   = blockIdx.y;
    const int tid = threadIdx.x;

    for (int i = tid; i < CIN; i += 128) {
        float s = S[b * CIN + i] + 1.0f;
        #pragma unroll
        for (int o = 0; o < COUT; ++o)
            wm[i * COUT + o] = weight[o * CIN + i] * s;
    }
    __syncthreads();

    const int p2 = blockIdx.x * 128 + tid;  // [0, 16384)
    const vf2* xb = (const vf2*)x    + (size_t)b * CIN  * SP2 + p2;
    const vf2* pv = (const vf2*)prev + (size_t)b * COUT * SP2 + p2;
    vf2*       yb = (vf2*)y          + (size_t)b * COUT * SP2 + p2;

    vf2 acc0 = {0,0}, acc1 = {0,0}, acc2 = {0,0}, acc3 = {0,0};
    const float4* wm4 = (const float4*)wm;  // wm4[i] = weights for o=0..3

    #pragma unroll 1
    for (int i = 0; i < CIN; i += 8) {
        vf2 xv[8];
        #pragma unroll
        for (int u = 0; u < 8; ++u)
            xv[u] = __builtin_nontemporal_load(&xb[(size_t)(i + u) * SP2]);
        #pragma unroll
        for (int u = 0; u < 8; ++u) {
            float4 w4 = wm4[i + u];   // LDS broadcast, conflict-free
            fma2(acc0, xv[u], w4.x);
            fma2(acc1, xv[u], w4.y);
            fma2(acc2, xv[u], w4.z);
            fma2(acc3, xv[u], w4.w);
        }
    }
    vf2 pr;
    pr = pv[0 * SP2]; yb[0 * SP2] = acc0 + pr;
    pr = pv[1 * SP2]; yb[1 * SP2] = acc1 + pr;
    pr = pv[2 * SP2]; yb[2 * SP2] = acc2 + pr;
    pr = pv[3 * SP2]; yb[3 * SP2] = acc3 + pr;
}

// Kernel 2: fused trilinear x2 upsample (half-pixel, jax.image.resize) + 3^3
// normalized blur [1,1.7,1] with edge padding. Separable: per axis, output 2k
// (even) = (1.175,2.275,0.25)/3.7 over y[k-1..k+1] (clamped); odd mirrored.
// One thread per 2x2x2 output cell; separable combine; nontemporal float2
// stores (out has zero reuse).
__global__ __launch_bounds__(256) void upblur_kernel(
    const float* __restrict__ y, float* __restrict__ out)
{
    constexpr float wA = 1.175f / 3.7f;   // near tap (even output)
    constexpr float wB = 2.275f / 3.7f;   // center tap
    constexpr float wC = 0.25f  / 3.7f;   // far tap

    const int c  = blockIdx.x * 256 + threadIdx.x;  // cell id in [0, 32*32768)
    const int ky = c & 31;
    const int kx = (c >> 5) & 31;
    const int kz = (c >> 10) & 31;
    const int bo = c >> 15;                          // (b*4+o) in [0,32)

    const float* yb = y + (size_t)bo * SP;
    const int zs[3] = { max(kz - 1, 0), kz, min(kz + 1, 31) };
    const int xs[3] = { max(kx - 1, 0), kx, min(kx + 1, 31) };
    const int ym = max(ky - 1, 0), yp = min(ky + 1, 31);

    // Stage 1: load 3x3x3 neighborhood, combine along y for both parities
    float se[3][3], so[3][3];
    #pragma unroll
    for (int a = 0; a < 3; ++a) {
        #pragma unroll
        for (int b2 = 0; b2 < 3; ++b2) {
            const float* row = yb + zs[a] * (ZDIM * ZDIM) + xs[b2] * ZDIM;
            float v0 = row[ym], v1 = row[ky], v2 = row[yp];
            se[a][b2] = wA * v0 + wB * v1 + wC * v2;   // yo = 2ky
            so[a][b2] = wC * v0 + wB * v1 + wA * v2;   // yo = 2ky+1
        }
    }
    // Stage 2: combine along x -> t[px][py][a]
    float t[2][2][3];
    #pragma unroll
    for (int a = 0; a < 3; ++a) {
        t[0][0][a] = wA * se[a][0] + wB * se[a][1] + wC * se[a][2];
        t[1][0][a] = wC * se[a][0] + wB * se[a][1] + wA * se[a][2];
        t[0][1][a] = wA * so[a][0] + wB * so[a][1] + wC * so[a][2];
        t[1][1][a] = wC * so[a][0] + wB * so[a][1] + wA * so[a][2];
    }
    // Stage 3: combine along z, write 2x2 vf2 (yo pair contiguous)
    const size_t obase = (size_t)bo * (64 * 64 * 64)
                       + (size_t)(2 * kz) * (64 * 64)
                       + (size_t)(2 * kx) * 64 + 2 * ky;
    #pragma unroll
    for (int pz = 0; pz < 2; ++pz) {
        const float w0 = pz ? wC : wA;
        const float w2 = pz ? wA : wC;
        #pragma unroll
        for (int px = 0; px < 2; ++px) {
            float oy0 = w0 * t[px][0][0] + wB * t[px][0][1] + w2 * t[px][0][2];
            float oy1 = w0 * t[px][1][0] + wB * t[px][1][1] + w2 * t[px][1][2];
            vf2 v = {oy0, oy1};
            __builtin_nontemporal_store(
                v, (vf2*)(out + obase + (size_t)pz * (64 * 64) + px * 64));
        }
    }
}

extern "C" void kernel_launch(void* const* d_in, const int* in_sizes, int n_in,
                              void* d_out, int out_size, void* d_ws, size_t ws_size,
                              hipStream_t stream) {
    const float* x      = (const float*)d_in[0];  // (8,256,32,32,32)
    const float* S      = (const float*)d_in[1];  // (8,256)
    const float* prev   = (const float*)d_in[2];  // (8,4,32,32,32)
    const float* weight = (const float*)d_in[3];  // (4,256)
    float* out = (float*)d_out;                   // (8,4,64,64,64)
    float* y   = (float*)d_ws;                    // (8,4,32,32,32) scratch, 4 MiB

    dim3 g1(SP2 / 128, BATCH);  // 128 x 8 = 1024 blocks of 128 threads
    modconv_kernel<<<g1, 128, 0, stream>>>(x, S, prev, weight, y);

    const int cells = BATCH * COUT * SP;  // 1,048,576 cells (2x2x2 outputs each)
    upblur_kernel<<<cells / 256, 256, 0, stream>>>(y, out);
}